// Round 2
// baseline (211.467 us; speedup 1.0000x reference)
//
#include <hip/hip_runtime.h>
#include <hip/hip_fp16.h>
#include <math.h>

#define SP 32768            // 32*32*32 voxels
#define PW 38               // padded volume width (zero ring around 34^3 logical)
#define PW2 (PW*PW)         // 1444
#define PVOX (PW*PW*PW)     // 54872
#define OMS 228             // om_s row stride (floats): 28-pt padded offs(2*84) + masks(2*28)

typedef short bf16x8 __attribute__((ext_vector_type(8)));
typedef unsigned short u16x4 __attribute__((ext_vector_type(4)));
typedef float f32x4 __attribute__((ext_vector_type(4)));

__device__ __forceinline__ unsigned short f2b(float f) {
    unsigned u = __float_as_uint(f);
    u = (u + 0x7FFFu + ((u >> 16) & 1u)) >> 16;   // RNE
    return (unsigned short)u;
}
__device__ __forceinline__ float b2f1(unsigned short s) {
    return __uint_as_float(((unsigned)s) << 16);
}
__device__ __forceinline__ __half2 h2(unsigned u) {
    return *reinterpret_cast<__half2*>(&u);
}

// ================= K1: prep (bf16 B^T weights) + x transpose + dwconv ==============
__global__ void k_front(const float* __restrict__ x, const float* __restrict__ dw,
                        const float* __restrict__ off_w, const float* __restrict__ mask_w,
                        const float* __restrict__ off_b, const float* __restrict__ mask_b,
                        const float* __restrict__ inp_w, const float* __restrict__ out_w,
                        unsigned short* __restrict__ WcatB, float* __restrict__ bcat,
                        unsigned short* __restrict__ inpB, unsigned short* __restrict__ outB,
                        unsigned short* __restrict__ x_tb,
                        unsigned short* __restrict__ xcb, float* __restrict__ partials) {
    int bb = blockIdx.x, tid = threadIdx.x;
    if (bb < 88) {                               // ---- weight prep ----
        int idx = bb * 256 + tid;
        int j = idx >> 6, k = idx & 63;
        if (j < 224) {
            float v = 0.f;
            if (j < 162) v = off_w[k * 162 + j];
            else if (j < 216) v = mask_w[k * 54 + (j - 162)];
            WcatB[j * 64 + k] = f2b(v);
            if (k == 0) bcat[j] = (j < 162) ? off_b[j] : (j < 216 ? mask_b[j - 162] : 0.f);
        } else if (j < 288) {
            outB[(j - 224) * 64 + k] = f2b(out_w[k * 64 + (j - 224)]);
        } else {
            inpB[(j - 288) * 64 + k] = f2b(inp_w[k * 64 + (j - 288)]);
        }
        return;
    }
    if (bb < 600) {                              // ---- x: NCDHW -> [s][c] bf16 ----
        __shared__ unsigned short tile[64][66];
        int s0 = (bb - 88) * 64;
        int row = tid >> 6, lane = tid & 63;
        for (int c = row; c < 64; c += 4)
            tile[c][lane] = f2b(x[(size_t)c * SP + s0 + lane]);
        __syncthreads();
        for (int r = row; r < 64; r += 4)
            x_tb[(size_t)(s0 + r) * 64 + lane] = tile[lane][r];
        return;
    }
    // ---- depthwise conv 3x3x3 + per-block sum/sumsq ----
    int b3 = bb - 600;
    int e = b3 * 256 + tid;
    int c = e >> 15, s = e & 32767;
    int d = s >> 10, h = (s >> 5) & 31, w = s & 31;
    const float* xs = x + (size_t)c * SP;
    const float* wt = dw + c * 27;
    float a = 0.f;
#pragma unroll
    for (int kd = 0; kd < 3; ++kd) {
        int zz = d + kd - 1; if ((unsigned)zz >= 32u) continue;
#pragma unroll
        for (int kh = 0; kh < 3; ++kh) {
            int yy = h + kh - 1; if ((unsigned)yy >= 32u) continue;
#pragma unroll
            for (int kw = 0; kw < 3; ++kw) {
                int xx = w + kw - 1; if ((unsigned)xx >= 32u) continue;
                a += xs[(zz << 10) + (yy << 5) + xx] * wt[kd * 9 + kh * 3 + kw];
            }
        }
    }
    xcb[e] = f2b(a);
    __shared__ float rs[256], rq[256];
    rs[tid] = a; rq[tid] = a * a;
    __syncthreads();
    for (int off = 128; off > 0; off >>= 1) {
        if (tid < off) { rs[tid] += rs[tid + off]; rq[tid] += rq[tid + off]; }
        __syncthreads();
    }
    if (tid == 0) {
        partials[b3 * 2 + 0] = rs[0];
        partials[b3 * 2 + 1] = rq[0];
    }
}

// ========= K2: GN+GELU -> x1b  |  MFMA inproj -> xpad (fp16)  |  ring zero =========
__global__ void k_mid(const unsigned short* __restrict__ xcb, const float* __restrict__ partials,
                      const float* __restrict__ gn_w, const float* __restrict__ gn_b,
                      unsigned short* __restrict__ x1b,
                      const unsigned short* __restrict__ x_tb,
                      const unsigned short* __restrict__ inpB,
                      const float* __restrict__ inp_b,
                      unsigned short* __restrict__ xpad) {
    int bb = blockIdx.x, tid = threadIdx.x;
    if (bb < 512) {                              // ---- GroupNorm(1,C)+GELU, transposed ----
        __shared__ float rs[256], rq[256];
        __shared__ unsigned short tile[64][66];
        float a = 0.f, b = 0.f;
        for (int i = tid; i < 8192; i += 256) { a += partials[2 * i]; b += partials[2 * i + 1]; }
        rs[tid] = a; rq[tid] = b;
        __syncthreads();
        for (int off = 128; off > 0; off >>= 1) {
            if (tid < off) { rs[tid] += rs[tid + off]; rq[tid] += rq[tid + off]; }
            __syncthreads();
        }
        const float Minv = 1.f / 2097152.f;
        float mu = rs[0] * Minv;
        float var = rq[0] * Minv - mu * mu;
        float rsq = rsqrtf(var + 1e-5f);
        int s0 = bb * 64;
        int row = tid >> 6, lane = tid & 63;
        for (int c = row; c < 64; c += 4) {
            float v = (b2f1(xcb[(size_t)c * SP + s0 + lane]) - mu) * rsq * gn_w[c] + gn_b[c];
            // gelu(tanh) = v * sigmoid(2t), t = 0.79788456*(v+0.044715 v^3)
            float t2 = 1.5957691216057308f * (v + 0.044715f * v * v * v);
            tile[c][lane] = f2b(v / (1.f + __expf(-t2)));
        }
        __syncthreads();
        for (int r = row; r < 64; r += 4)
            x1b[(size_t)(s0 + r) * 64 + lane] = tile[lane][r];
        return;
    }
    if (bb < 1024) {                             // ---- inproj: 4 waves x 16 voxels ----
        int wv = tid >> 6, lane = tid & 63;
        int quad = lane >> 4, col = lane & 15;
        int s0 = (bb - 512) * 64 + wv * 16;
        bf16x8 a0 = *(const bf16x8*)(x_tb + (size_t)(s0 + col) * 64 + quad * 8);
        bf16x8 a1 = *(const bf16x8*)(x_tb + (size_t)(s0 + col) * 64 + 32 + quad * 8);
        int vp[4];
#pragma unroll
        for (int r = 0; r < 4; ++r) {
            int s = s0 + (quad << 2) + r;        // orig voxel (d,h,w) at 38-coord +2
            vp[r] = (((s >> 10) + 2) * PW + ((s >> 5) & 31) + 2) * PW + (s & 31) + 2;
        }
#pragma unroll
        for (int nt = 0; nt < 4; ++nt) {
            int n0 = nt * 16;
            bf16x8 b0 = *(const bf16x8*)(inpB + (n0 + col) * 64 + quad * 8);
            bf16x8 b1 = *(const bf16x8*)(inpB + (n0 + col) * 64 + 32 + quad * 8);
            f32x4 c = {0.f, 0.f, 0.f, 0.f};
            c = __builtin_amdgcn_mfma_f32_16x16x32_bf16(a0, b0, c, 0, 0, 0);
            c = __builtin_amdgcn_mfma_f32_16x16x32_bf16(a1, b1, c, 0, 0, 0);
            float bq = inp_b[n0 + col];
#pragma unroll
            for (int r = 0; r < 4; ++r)
                xpad[(size_t)vp[r] * 64 + n0 + col] =
                    __half_as_ushort(__float2half(c[r] + bq));
        }
        return;
    }
    // ---- ring zero (fp16): 16 voxels x 16 8-byte slots per 256 threads, 4 iters ----
    int cblk = bb - 1024;
    int j = tid >> 4, c4 = tid & 15;
    u16x4 z = {0, 0, 0, 0};
#pragma unroll
    for (int k = 0; k < 4; ++k) {
        int v = cblk * 64 + k * 16 + j;
        if (v >= PVOX) break;
        int zz = v / PW2, r = v - zz * PW2, yy = r / PW, xx = r - yy * PW;
        if (zz < 2 || zz > 33 || yy < 2 || yy > 33 || xx < 2 || xx > 33)
            *(u16x4*)(xpad + (size_t)v * 64 + c4 * 4) = z;
    }
}

// ---- 27-point sampler, 4 fp16 channels/lane (uint2 loads, 2 half2 lanes of math) ----
__device__ __forceinline__ void sample27_4(const float* __restrict__ orow,
                                           const float* __restrict__ mrow,
                                           const char* __restrict__ volc,
                                           float xb, float yb, float zb,
                                           float* __restrict__ acc) {
#pragma unroll
    for (int p = 0; p < 27; ++p) {
        const int px = p % 3, py = (p / 3) % 3, pz = p / 9;
        float ox = orow[p * 3 + 0], oy = orow[p * 3 + 1], oz = orow[p * 3 + 2];
        float mk = mrow[p];
        float ix = __builtin_fmaf(0.25f, ox, xb + (float)px);
        float iy = __builtin_fmaf(0.5f, oy, yb + (float)py);
        float iz = __builtin_fmaf(0.5f, oz, zb + (float)pz);
        // clamp to [0,36]: OOB samples land wholly in the zero ring
        ix = fminf(fmaxf(ix, 0.f), 36.f);
        iy = fminf(fmaxf(iy, 0.f), 36.f);
        iz = fminf(fmaxf(iz, 0.f), 36.f);
        float xf = floorf(ix), yf = floorf(iy), zf = floorf(iz);
        float fx = ix - xf, fy = iy - yf, fz = iz - zf;
        float fi = __builtin_fmaf(zf, (float)PW2, __builtin_fmaf(yf, (float)PW, xf));
        int ib = ((int)fi) << 7;                 // 128 B per voxel row (fp16)
        const char* base = volc + ib;
        uint2 r000 = *(const uint2*)(base);
        uint2 r001 = *(const uint2*)(base + 128);
        uint2 r010 = *(const uint2*)(base + PW * 128);
        uint2 r011 = *(const uint2*)(base + PW * 128 + 128);
        uint2 r100 = *(const uint2*)(base + PW2 * 128);
        uint2 r101 = *(const uint2*)(base + PW2 * 128 + 128);
        uint2 r110 = *(const uint2*)(base + (PW2 + PW) * 128);
        uint2 r111 = *(const uint2*)(base + (PW2 + PW) * 128 + 128);
        __half2 fx2 = __float2half2_rn(fx);
        __half2 fy2 = __float2half2_rn(fy);
        __half2 fz2 = __float2half2_rn(fz);
        #define TRI(comp, ci)                                                   \
        {                                                                       \
            __half2 t0 = __hfma2(fx2, __hsub2(h2(r001.comp), h2(r000.comp)), h2(r000.comp)); \
            __half2 t1 = __hfma2(fx2, __hsub2(h2(r011.comp), h2(r010.comp)), h2(r010.comp)); \
            __half2 t2 = __hfma2(fx2, __hsub2(h2(r101.comp), h2(r100.comp)), h2(r100.comp)); \
            __half2 t3 = __hfma2(fx2, __hsub2(h2(r111.comp), h2(r110.comp)), h2(r110.comp)); \
            __half2 u0 = __hfma2(fy2, __hsub2(t1, t0), t0);                     \
            __half2 u1 = __hfma2(fy2, __hsub2(t3, t2), t2);                     \
            __half2 rr = __hfma2(fz2, __hsub2(u1, u0), u0);                     \
            float2 ff = __half22float2(rr);                                     \
            acc[2 * ci + 0] = __builtin_fmaf(mk, ff.x, acc[2 * ci + 0]);        \
            acc[2 * ci + 1] = __builtin_fmaf(mk, ff.y, acc[2 * ci + 1]);        \
        }
        TRI(x, 0) TRI(y, 1)
        #undef TRI
    }
}

// ========= K3: main — 16 vox/block, 4 waves, lane = (voxel, 4-channel slice) =========
// 32 waves/CU target occupancy; 2 barriers; in-wave softmax; direct global store.
__global__ void __launch_bounds__(256, 8) k_main(const unsigned short* __restrict__ x1b,
                                                 const unsigned short* __restrict__ xpad,
                                                 const unsigned short* __restrict__ WcatB,
                                                 const float* __restrict__ bcat,
                                                 const unsigned short* __restrict__ outB,
                                                 const float* __restrict__ out_b,
                                                 float* __restrict__ out) {
    __shared__ float om_s[16 * OMS];             // 14592 B: 28-pt padded offs+masks
    __shared__ unsigned short smb[16 * 72];      // 2304 B: sampled accum, bf16 (stride 72)
    int tid = threadIdx.x, wv = tid >> 6, lane = tid & 63;
    int quad = lane >> 4, col = lane & 15;
    // XCD swizzle: blocks sharing (blk&7) land on one XCD, contiguous 4096-voxel slab
    int sb = ((blockIdx.x & 7) << 8) | (blockIdx.x >> 3);
    int s0 = sb * 16;                            // 16 voxels per block
    // ---- phase 1: offset+mask GEMM (16x64)@(64x224); 14 jt tiles over 4 waves ----
    {
        bf16x8 a0 = *(const bf16x8*)(x1b + (size_t)(s0 + col) * 64 + quad * 8);
        bf16x8 a1 = *(const bf16x8*)(x1b + (size_t)(s0 + col) * 64 + 32 + quad * 8);
        for (int jt = wv; jt < 14; jt += 4) {
            int n0 = jt * 16;
            bf16x8 b0 = *(const bf16x8*)(WcatB + (n0 + col) * 64 + quad * 8);
            bf16x8 b1 = *(const bf16x8*)(WcatB + (n0 + col) * 64 + 32 + quad * 8);
            f32x4 c = {0.f, 0.f, 0.f, 0.f};
            c = __builtin_amdgcn_mfma_f32_16x16x32_bf16(a0, b0, c, 0, 0, 0);
            c = __builtin_amdgcn_mfma_f32_16x16x32_bf16(a1, b1, c, 0, 0, 0);
            float bb = bcat[n0 + col];
            // remap feature n -> padded 28-pt slot
            int n = n0 + col, slot;
            if (n < 162) slot = n + ((n >= 81) ? 3 : 0);
            else { int n2 = n - 162; slot = 168 + n2 + ((n2 >= 27) ? 1 : 0); }
            if (n < 216) {
#pragma unroll
                for (int r = 0; r < 4; ++r)
                    om_s[(quad * 4 + r) * OMS + slot] = c[r] + bb;
            }
        }
    }
    __syncthreads();
    // ---- phase 2: wave-parallel softmax; wave owns its 4 voxels = 8 rows, 8 lanes/row ----
    // Same wave consumes its own rows in phase 3 -> no barrier needed after this.
    {
        int row = lane >> 3, sub = lane & 7;     // 8 rows/wave, 8 lanes/row, 4 pts/lane
        int vloc = wv * 4 + (row >> 1), g = row & 1;
        float* m = &om_s[vloc * OMS + 168 + g * 28];
        float mv[4];
        float mx = -1e30f;
#pragma unroll
        for (int i = 0; i < 4; ++i) {
            int p = sub * 4 + i;
            mv[i] = (p < 27) ? m[p] : -1e30f;
            mx = fmaxf(mx, mv[i]);
        }
        mx = fmaxf(mx, __shfl_xor(mx, 1));
        mx = fmaxf(mx, __shfl_xor(mx, 2));
        mx = fmaxf(mx, __shfl_xor(mx, 4));
        float e[4], sm = 0.f;
#pragma unroll
        for (int i = 0; i < 4; ++i) { e[i] = __expf(mv[i] - mx); sm += e[i]; }
        sm += __shfl_xor(sm, 1);
        sm += __shfl_xor(sm, 2);
        sm += __shfl_xor(sm, 4);
        float inv = 1.f / sm;
#pragma unroll
        for (int i = 0; i < 4; ++i) {
            int p = sub * 4 + i;
            if (p < 27) m[p] = e[i] * inv;
        }
    }
    // ---- phase 3: sampling; wave wv owns voxels wv*4..wv*4+3; 4 fp16 channels/lane ----
    {
        int v = wv * 4 + (lane >> 4);            // local voxel 0..15
        int oc = lane & 15, gg = oc >> 3;        // channels oc*4..oc*4+3
        int sv = s0 + v;
        float zb = (float)((sv >> 10) + 1);
        float yb = (float)(((sv >> 5) & 31) + 1);
        float xb = (float)((sv & 31) + 1);
        const float* orow = &om_s[v * OMS + gg * 84];
        const float* mrow = &om_s[v * OMS + 168 + gg * 28];
        const char* volc = (const char*)xpad + oc * 8;      // 4 fp16 channels
        float acc[4] = {0.f, 0.f, 0.f, 0.f};
        sample27_4(orow, mrow, volc, xb, yb, zb, acc);
        u16x4 sb4;
#pragma unroll
        for (int k = 0; k < 4; ++k) sb4[k] = f2b(acc[k]);
        *(u16x4*)(smb + v * 72 + oc * 4) = sb4;
    }
    __syncthreads();
    // ---- phase 4: out projection (16x64)@(64x64); wave wv does col tile wv ----
    // Store directly to global from MFMA regs (no obuf, no extra barrier).
    {
        bf16x8 oa0 = *(const bf16x8*)(smb + col * 72 + quad * 8);
        bf16x8 oa1 = *(const bf16x8*)(smb + col * 72 + 32 + quad * 8);
        int n0 = wv * 16;
        bf16x8 b0 = *(const bf16x8*)(outB + (n0 + col) * 64 + quad * 8);
        bf16x8 b1 = *(const bf16x8*)(outB + (n0 + col) * 64 + 32 + quad * 8);
        f32x4 c = {0.f, 0.f, 0.f, 0.f};
        c = __builtin_amdgcn_mfma_f32_16x16x32_bf16(oa0, b0, c, 0, 0, 0);
        c = __builtin_amdgcn_mfma_f32_16x16x32_bf16(oa1, b1, c, 0, 0, 0);
        float bb = out_b[n0 + col];
#pragma unroll
        for (int r = 0; r < 4; ++r)
            out[(size_t)(s0 + quad * 4 + r) * 64 + n0 + col] = c[r] + bb;
    }
}

extern "C" void kernel_launch(void* const* d_in, const int* in_sizes, int n_in,
                              void* d_out, int out_size, void* d_ws, size_t ws_size,
                              hipStream_t stream) {
    const float* x      = (const float*)d_in[0];
    const float* dw_w   = (const float*)d_in[1];
    const float* gn_w   = (const float*)d_in[2];
    const float* gn_b   = (const float*)d_in[3];
    const float* inp_w  = (const float*)d_in[4];
    const float* inp_b  = (const float*)d_in[5];
    const float* off_w  = (const float*)d_in[6];
    const float* off_b  = (const float*)d_in[7];
    const float* mask_w = (const float*)d_in[8];
    const float* mask_b = (const float*)d_in[9];
    const float* out_w  = (const float*)d_in[10];
    const float* out_b  = (const float*)d_in[11];

    char* B = (char*)d_ws;
    float*          partials = (float*)(B + 256);                // 64 KB
    unsigned short* xcb      = (unsigned short*)(B + 65792);     // 4 MB (bf16)
    unsigned short* x1b      = (unsigned short*)(B + 8454400);   // 4 MB
    unsigned short* x_tb     = (unsigned short*)(B + 12648704);  // 4 MB
    unsigned short* xpad     = (unsigned short*)(B + 16843008);  // 7.02 MB (fp16)
    unsigned short* WcatB    = (unsigned short*)(B + 30890240);  // 28 KB
    float*          bcat     = (float*)(B + 30918912);           // 1 KB
    unsigned short* inpB     = (unsigned short*)(B + 30919936);  // 8 KB
    unsigned short* outB     = (unsigned short*)(B + 30928128);  // 8 KB
    float* out = (float*)d_out;

    k_front<<<8792, 256, 0, stream>>>(x, dw_w, off_w, mask_w, off_b, mask_b,
                                      inp_w, out_w, WcatB, bcat, inpB, outB,
                                      x_tb, xcb, partials);
    k_mid<<<512 + 512 + 858, 256, 0, stream>>>(xcb, partials, gn_w, gn_b, x1b,
                                               x_tb, inpB, inp_b, xpad);
    k_main<<<2048, 256, 0, stream>>>(x1b, xpad, WcatB, bcat, outB, out_b, out);
}

// Round 3
// 177.599 us; speedup vs baseline: 1.1907x; 1.1907x over previous
//
#include <hip/hip_runtime.h>
#include <hip/hip_fp16.h>
#include <math.h>

#define SP 32768            // 32*32*32 voxels
#define PW 38               // padded volume width (zero ring around 34^3 logical)
#define PW2 (PW*PW)         // 1444
#define PVOX (PW*PW*PW)     // 54872
#define OMS 228             // om_s row stride (floats): 28-pt padded offs(2*84) + masks(2*28)

typedef short bf16x8 __attribute__((ext_vector_type(8)));
typedef unsigned short u16x4 __attribute__((ext_vector_type(4)));
typedef float f32x4 __attribute__((ext_vector_type(4)));

__device__ __forceinline__ unsigned short f2b(float f) {
    unsigned u = __float_as_uint(f);
    u = (u + 0x7FFFu + ((u >> 16) & 1u)) >> 16;   // RNE
    return (unsigned short)u;
}
__device__ __forceinline__ float b2f1(unsigned short s) {
    return __uint_as_float(((unsigned)s) << 16);
}
__device__ __forceinline__ __half2 h2(unsigned u) {
    return *reinterpret_cast<__half2*>(&u);
}

// ================= K1: prep (bf16 B^T weights) + x transpose + dwconv ==============
__global__ void k_front(const float* __restrict__ x, const float* __restrict__ dw,
                        const float* __restrict__ off_w, const float* __restrict__ mask_w,
                        const float* __restrict__ off_b, const float* __restrict__ mask_b,
                        const float* __restrict__ inp_w, const float* __restrict__ out_w,
                        unsigned short* __restrict__ WcatB, float* __restrict__ bcat,
                        unsigned short* __restrict__ inpB, unsigned short* __restrict__ outB,
                        unsigned short* __restrict__ x_tb,
                        unsigned short* __restrict__ xcb, float* __restrict__ partials) {
    int bb = blockIdx.x, tid = threadIdx.x;
    if (bb < 88) {                               // ---- weight prep ----
        int idx = bb * 256 + tid;
        int j = idx >> 6, k = idx & 63;
        if (j < 224) {
            float v = 0.f;
            if (j < 162) v = off_w[k * 162 + j];
            else if (j < 216) v = mask_w[k * 54 + (j - 162)];
            WcatB[j * 64 + k] = f2b(v);
            if (k == 0) bcat[j] = (j < 162) ? off_b[j] : (j < 216 ? mask_b[j - 162] : 0.f);
        } else if (j < 288) {
            outB[(j - 224) * 64 + k] = f2b(out_w[k * 64 + (j - 224)]);
        } else {
            inpB[(j - 288) * 64 + k] = f2b(inp_w[k * 64 + (j - 288)]);
        }
        return;
    }
    if (bb < 600) {                              // ---- x: NCDHW -> [s][c] bf16 ----
        __shared__ unsigned short tile[64][66];
        int s0 = (bb - 88) * 64;
        int row = tid >> 6, lane = tid & 63;
        for (int c = row; c < 64; c += 4)
            tile[c][lane] = f2b(x[(size_t)c * SP + s0 + lane]);
        __syncthreads();
        for (int r = row; r < 64; r += 4)
            x_tb[(size_t)(s0 + r) * 64 + lane] = tile[lane][r];
        return;
    }
    // ---- depthwise conv 3x3x3 + per-block sum/sumsq ----
    int b3 = bb - 600;
    int e = b3 * 256 + tid;
    int c = e >> 15, s = e & 32767;
    int d = s >> 10, h = (s >> 5) & 31, w = s & 31;
    const float* xs = x + (size_t)c * SP;
    const float* wt = dw + c * 27;
    float a = 0.f;
#pragma unroll
    for (int kd = 0; kd < 3; ++kd) {
        int zz = d + kd - 1; if ((unsigned)zz >= 32u) continue;
#pragma unroll
        for (int kh = 0; kh < 3; ++kh) {
            int yy = h + kh - 1; if ((unsigned)yy >= 32u) continue;
#pragma unroll
            for (int kw = 0; kw < 3; ++kw) {
                int xx = w + kw - 1; if ((unsigned)xx >= 32u) continue;
                a += xs[(zz << 10) + (yy << 5) + xx] * wt[kd * 9 + kh * 3 + kw];
            }
        }
    }
    xcb[e] = f2b(a);
    __shared__ float rs[256], rq[256];
    rs[tid] = a; rq[tid] = a * a;
    __syncthreads();
    for (int off = 128; off > 0; off >>= 1) {
        if (tid < off) { rs[tid] += rs[tid + off]; rq[tid] += rq[tid + off]; }
        __syncthreads();
    }
    if (tid == 0) {
        partials[b3 * 2 + 0] = rs[0];
        partials[b3 * 2 + 1] = rq[0];
    }
}

// ========= K2: GN+GELU -> x1b  |  MFMA inproj -> xpad (fp16)  |  ring zero =========
__global__ void k_mid(const unsigned short* __restrict__ xcb, const float* __restrict__ partials,
                      const float* __restrict__ gn_w, const float* __restrict__ gn_b,
                      unsigned short* __restrict__ x1b,
                      const unsigned short* __restrict__ x_tb,
                      const unsigned short* __restrict__ inpB,
                      const float* __restrict__ inp_b,
                      unsigned short* __restrict__ xpad) {
    int bb = blockIdx.x, tid = threadIdx.x;
    if (bb < 512) {                              // ---- GroupNorm(1,C)+GELU, transposed ----
        __shared__ float rs[256], rq[256];
        __shared__ unsigned short tile[64][66];
        float a = 0.f, b = 0.f;
        for (int i = tid; i < 8192; i += 256) { a += partials[2 * i]; b += partials[2 * i + 1]; }
        rs[tid] = a; rq[tid] = b;
        __syncthreads();
        for (int off = 128; off > 0; off >>= 1) {
            if (tid < off) { rs[tid] += rs[tid + off]; rq[tid] += rq[tid + off]; }
            __syncthreads();
        }
        const float Minv = 1.f / 2097152.f;
        float mu = rs[0] * Minv;
        float var = rq[0] * Minv - mu * mu;
        float rsq = rsqrtf(var + 1e-5f);
        int s0 = bb * 64;
        int row = tid >> 6, lane = tid & 63;
        for (int c = row; c < 64; c += 4) {
            float v = (b2f1(xcb[(size_t)c * SP + s0 + lane]) - mu) * rsq * gn_w[c] + gn_b[c];
            // gelu(tanh) = v * sigmoid(2t), t = 0.79788456*(v+0.044715 v^3)
            float t2 = 1.5957691216057308f * (v + 0.044715f * v * v * v);
            tile[c][lane] = f2b(v / (1.f + __expf(-t2)));
        }
        __syncthreads();
        for (int r = row; r < 64; r += 4)
            x1b[(size_t)(s0 + r) * 64 + lane] = tile[lane][r];
        return;
    }
    if (bb < 1024) {                             // ---- inproj: 4 waves x 16 voxels ----
        int wv = tid >> 6, lane = tid & 63;
        int quad = lane >> 4, col = lane & 15;
        int s0 = (bb - 512) * 64 + wv * 16;
        bf16x8 a0 = *(const bf16x8*)(x_tb + (size_t)(s0 + col) * 64 + quad * 8);
        bf16x8 a1 = *(const bf16x8*)(x_tb + (size_t)(s0 + col) * 64 + 32 + quad * 8);
        int vp[4];
#pragma unroll
        for (int r = 0; r < 4; ++r) {
            int s = s0 + (quad << 2) + r;        // orig voxel (d,h,w) at 38-coord +2
            vp[r] = (((s >> 10) + 2) * PW + ((s >> 5) & 31) + 2) * PW + (s & 31) + 2;
        }
#pragma unroll
        for (int nt = 0; nt < 4; ++nt) {
            int n0 = nt * 16;
            bf16x8 b0 = *(const bf16x8*)(inpB + (n0 + col) * 64 + quad * 8);
            bf16x8 b1 = *(const bf16x8*)(inpB + (n0 + col) * 64 + 32 + quad * 8);
            f32x4 c = {0.f, 0.f, 0.f, 0.f};
            c = __builtin_amdgcn_mfma_f32_16x16x32_bf16(a0, b0, c, 0, 0, 0);
            c = __builtin_amdgcn_mfma_f32_16x16x32_bf16(a1, b1, c, 0, 0, 0);
            float bq = inp_b[n0 + col];
#pragma unroll
            for (int r = 0; r < 4; ++r)
                xpad[(size_t)vp[r] * 64 + n0 + col] =
                    __half_as_ushort(__float2half(c[r] + bq));
        }
        return;
    }
    // ---- ring zero (fp16): 16 voxels x 16 8-byte slots per 256 threads, 4 iters ----
    int cblk = bb - 1024;
    int j = tid >> 4, c4 = tid & 15;
    u16x4 z = {0, 0, 0, 0};
#pragma unroll
    for (int k = 0; k < 4; ++k) {
        int v = cblk * 64 + k * 16 + j;
        if (v >= PVOX) break;
        int zz = v / PW2, r = v - zz * PW2, yy = r / PW, xx = r - yy * PW;
        if (zz < 2 || zz > 33 || yy < 2 || yy > 33 || xx < 2 || xx > 33)
            *(u16x4*)(xpad + (size_t)v * 64 + c4 * 4) = z;
    }
}

// ---- paired-point sampler: two independent register streams per iteration ----
// 28 points (27 real + 1 zero-mask dummy at slot 27); 8 fp16 channels/lane (uint4).
__device__ __forceinline__ void samplePairs(const float* __restrict__ orow,
                                            const float* __restrict__ mrow,
                                            const char* __restrict__ volc,
                                            float xb, float yb, float zb,
                                            float* __restrict__ accA,
                                            float* __restrict__ accB) {
#pragma unroll
    for (int i = 0; i < 14; ++i) {
        const int pA = 2 * i, pB = 2 * i + 1;
        const int pxA = pA % 3, pyA = (pA / 3) % 3, pzA = pA / 9;
        const int pxB = pB % 3, pyB = (pB / 3) % 3, pzB = pB / 9;  // p=27 -> (0,0,3) dummy
        // ---- addresses for both points first (loads can all issue early) ----
        float oxA = orow[pA * 3 + 0], oyA = orow[pA * 3 + 1], ozA = orow[pA * 3 + 2];
        float oxB = orow[pB * 3 + 0], oyB = orow[pB * 3 + 1], ozB = orow[pB * 3 + 2];
        float mkA = mrow[pA], mkB = mrow[pB];
        float ixA = __builtin_fmaf(0.25f, oxA, xb + (float)pxA);
        float iyA = __builtin_fmaf(0.5f, oyA, yb + (float)pyA);
        float izA = __builtin_fmaf(0.5f, ozA, zb + (float)pzA);
        float ixB = __builtin_fmaf(0.25f, oxB, xb + (float)pxB);
        float iyB = __builtin_fmaf(0.5f, oyB, yb + (float)pyB);
        float izB = __builtin_fmaf(0.5f, ozB, zb + (float)pzB);
        ixA = fminf(fmaxf(ixA, 0.f), 36.f);
        iyA = fminf(fmaxf(iyA, 0.f), 36.f);
        izA = fminf(fmaxf(izA, 0.f), 36.f);
        ixB = fminf(fmaxf(ixB, 0.f), 36.f);
        iyB = fminf(fmaxf(iyB, 0.f), 36.f);
        izB = fminf(fmaxf(izB, 0.f), 36.f);
        float xfA = floorf(ixA), yfA = floorf(iyA), zfA = floorf(izA);
        float xfB = floorf(ixB), yfB = floorf(iyB), zfB = floorf(izB);
        float fxA = ixA - xfA, fyA = iyA - yfA, fzA = izA - zfA;
        float fxB = ixB - xfB, fyB = iyB - yfB, fzB = izB - zfB;
        float fiA = __builtin_fmaf(zfA, (float)PW2, __builtin_fmaf(yfA, (float)PW, xfA));
        float fiB = __builtin_fmaf(zfB, (float)PW2, __builtin_fmaf(yfB, (float)PW, xfB));
        const char* baseA = volc + (((int)fiA) << 7);    // 128 B per voxel row (fp16)
        const char* baseB = volc + (((int)fiB) << 7);
        // ---- 16 independent gather loads (8 per point) ----
        uint4 a000 = *(const uint4*)(baseA);
        uint4 a001 = *(const uint4*)(baseA + 128);
        uint4 a010 = *(const uint4*)(baseA + PW * 128);
        uint4 a011 = *(const uint4*)(baseA + PW * 128 + 128);
        uint4 a100 = *(const uint4*)(baseA + PW2 * 128);
        uint4 a101 = *(const uint4*)(baseA + PW2 * 128 + 128);
        uint4 a110 = *(const uint4*)(baseA + (PW2 + PW) * 128);
        uint4 a111 = *(const uint4*)(baseA + (PW2 + PW) * 128 + 128);
        uint4 b000 = *(const uint4*)(baseB);
        uint4 b001 = *(const uint4*)(baseB + 128);
        uint4 b010 = *(const uint4*)(baseB + PW * 128);
        uint4 b011 = *(const uint4*)(baseB + PW * 128 + 128);
        uint4 b100 = *(const uint4*)(baseB + PW2 * 128);
        uint4 b101 = *(const uint4*)(baseB + PW2 * 128 + 128);
        uint4 b110 = *(const uint4*)(baseB + (PW2 + PW) * 128);
        uint4 b111 = *(const uint4*)(baseB + (PW2 + PW) * 128 + 128);
        // ---- math A (only waits on A loads; B loads still in flight) ----
        {
            __half2 fx2 = __float2half2_rn(fxA);
            __half2 fy2 = __float2half2_rn(fyA);
            __half2 fz2 = __float2half2_rn(fzA);
            #define TRI(comp, ci)                                                   \
            {                                                                       \
                __half2 t0 = __hfma2(fx2, __hsub2(h2(a001.comp), h2(a000.comp)), h2(a000.comp)); \
                __half2 t1 = __hfma2(fx2, __hsub2(h2(a011.comp), h2(a010.comp)), h2(a010.comp)); \
                __half2 t2 = __hfma2(fx2, __hsub2(h2(a101.comp), h2(a100.comp)), h2(a100.comp)); \
                __half2 t3 = __hfma2(fx2, __hsub2(h2(a111.comp), h2(a110.comp)), h2(a110.comp)); \
                __half2 u0 = __hfma2(fy2, __hsub2(t1, t0), t0);                     \
                __half2 u1 = __hfma2(fy2, __hsub2(t3, t2), t2);                     \
                __half2 rr = __hfma2(fz2, __hsub2(u1, u0), u0);                     \
                float2 ff = __half22float2(rr);                                     \
                accA[2 * ci + 0] = __builtin_fmaf(mkA, ff.x, accA[2 * ci + 0]);     \
                accA[2 * ci + 1] = __builtin_fmaf(mkA, ff.y, accA[2 * ci + 1]);     \
            }
            TRI(x, 0) TRI(y, 1) TRI(z, 2) TRI(w, 3)
            #undef TRI
        }
        // ---- math B ----
        {
            __half2 fx2 = __float2half2_rn(fxB);
            __half2 fy2 = __float2half2_rn(fyB);
            __half2 fz2 = __float2half2_rn(fzB);
            #define TRI(comp, ci)                                                   \
            {                                                                       \
                __half2 t0 = __hfma2(fx2, __hsub2(h2(b001.comp), h2(b000.comp)), h2(b000.comp)); \
                __half2 t1 = __hfma2(fx2, __hsub2(h2(b011.comp), h2(b010.comp)), h2(b010.comp)); \
                __half2 t2 = __hfma2(fx2, __hsub2(h2(b101.comp), h2(b100.comp)), h2(b100.comp)); \
                __half2 t3 = __hfma2(fx2, __hsub2(h2(b111.comp), h2(b110.comp)), h2(b110.comp)); \
                __half2 u0 = __hfma2(fy2, __hsub2(t1, t0), t0);                     \
                __half2 u1 = __hfma2(fy2, __hsub2(t3, t2), t2);                     \
                __half2 rr = __hfma2(fz2, __hsub2(u1, u0), u0);                     \
                float2 ff = __half22float2(rr);                                     \
                accB[2 * ci + 0] = __builtin_fmaf(mkB, ff.x, accB[2 * ci + 0]);     \
                accB[2 * ci + 1] = __builtin_fmaf(mkB, ff.y, accB[2 * ci + 1]);     \
            }
            TRI(x, 0) TRI(y, 1) TRI(z, 2) TRI(w, 3)
            #undef TRI
        }
    }
}

// ========= K3: main — 16 vox/block, 2 waves, each wave owns 8 voxels x 28 pts =========
// 2 barriers; in-wave softmax; paired-point ILP sampler; direct global store.
__global__ void __launch_bounds__(128, 4) k_main(const unsigned short* __restrict__ x1b,
                                                 const unsigned short* __restrict__ xpad,
                                                 const unsigned short* __restrict__ WcatB,
                                                 const float* __restrict__ bcat,
                                                 const unsigned short* __restrict__ outB,
                                                 const float* __restrict__ out_b,
                                                 float* __restrict__ out) {
    __shared__ float om_s[16 * OMS];             // 14592 B: 28-pt padded offs+masks
    __shared__ unsigned short smb[16 * 72];      // 2304 B: sampled accum, bf16 (stride 72)
    int tid = threadIdx.x, wv = tid >> 6, lane = tid & 63;
    int quad = lane >> 4, col = lane & 15;
    // XCD swizzle: blocks sharing (blk&7) land on one XCD, contiguous 4096-voxel slab
    int sb = ((blockIdx.x & 7) << 8) | (blockIdx.x >> 3);
    int s0 = sb * 16;                            // 16 voxels per block
    // ---- phase 1: offset+mask GEMM (16x64)@(64x224); 7 jt tiles per wave ----
    {
        bf16x8 a0 = *(const bf16x8*)(x1b + (size_t)(s0 + col) * 64 + quad * 8);
        bf16x8 a1 = *(const bf16x8*)(x1b + (size_t)(s0 + col) * 64 + 32 + quad * 8);
        for (int jt = wv; jt < 14; jt += 2) {
            int n0 = jt * 16;
            bf16x8 b0 = *(const bf16x8*)(WcatB + (n0 + col) * 64 + quad * 8);
            bf16x8 b1 = *(const bf16x8*)(WcatB + (n0 + col) * 64 + 32 + quad * 8);
            f32x4 c = {0.f, 0.f, 0.f, 0.f};
            c = __builtin_amdgcn_mfma_f32_16x16x32_bf16(a0, b0, c, 0, 0, 0);
            c = __builtin_amdgcn_mfma_f32_16x16x32_bf16(a1, b1, c, 0, 0, 0);
            float bb = bcat[n0 + col];
            // remap feature n -> padded 28-pt slot
            int n = n0 + col, slot;
            if (n < 162) slot = n + ((n >= 81) ? 3 : 0);
            else { int n2 = n - 162; slot = 168 + n2 + ((n2 >= 27) ? 1 : 0); }
            if (n < 216) {
#pragma unroll
                for (int r = 0; r < 4; ++r)
                    om_s[(quad * 4 + r) * OMS + slot] = c[r] + bb;
            }
        }
    }
    __syncthreads();
    // ---- phase 2: wave-parallel softmax; 16 rows/wave (8 vox x 2 grp), 4 lanes/row ----
    // Same wave consumes its own rows in phase 3 -> no barrier needed after this.
    {
        int row = lane >> 2, sub = lane & 3;     // 4 lanes per row, 7 pts per lane
        int vloc = wv * 8 + (row >> 1), g = row & 1;
        float* m = &om_s[vloc * OMS + 168 + g * 28];
        float mv[7];
        float mx = -1e30f;
#pragma unroll
        for (int i = 0; i < 7; ++i) {
            int p = sub * 7 + i;
            mv[i] = (p < 27) ? m[p] : -1e30f;
            mx = fmaxf(mx, mv[i]);
        }
        mx = fmaxf(mx, __shfl_xor(mx, 1));
        mx = fmaxf(mx, __shfl_xor(mx, 2));
        float e[7], sm = 0.f;
#pragma unroll
        for (int i = 0; i < 7; ++i) { e[i] = __expf(mv[i] - mx); sm += e[i]; }
        sm += __shfl_xor(sm, 1);
        sm += __shfl_xor(sm, 2);
        float inv = 1.f / sm;
#pragma unroll
        for (int i = 0; i < 7; ++i) {
            int p = sub * 7 + i;
            if (p < 27) m[p] = e[i] * inv;
        }
        // dummy point 27: zero mask + zero offsets so the paired sampler is safe
        if (sub == 3) m[27] = 0.f;
        float* o = &om_s[vloc * OMS + g * 84];
        if (sub < 3) o[81 + sub] = 0.f;
    }
    // ---- phase 3: sampling; wave wv owns voxels wv*8..wv*8+7; 2-point ILP streams ----
    {
        int v = wv * 8 + (lane >> 3);            // local voxel 0..15
        int oct = lane & 7, gg = oct >> 2;       // channels oct*8..oct*8+7
        int sv = s0 + v;
        float zb = (float)((sv >> 10) + 1);
        float yb = (float)(((sv >> 5) & 31) + 1);
        float xb = (float)((sv & 31) + 1);
        const float* orow = &om_s[v * OMS + gg * 84];
        const float* mrow = &om_s[v * OMS + 168 + gg * 28];
        const char* volc = (const char*)xpad + oct * 16;    // 8 fp16 channels
        float accA[8] = {0.f, 0.f, 0.f, 0.f, 0.f, 0.f, 0.f, 0.f};
        float accB[8] = {0.f, 0.f, 0.f, 0.f, 0.f, 0.f, 0.f, 0.f};
        samplePairs(orow, mrow, volc, xb, yb, zb, accA, accB);
        bf16x8 sb8;
#pragma unroll
        for (int k = 0; k < 8; ++k) sb8[k] = (short)f2b(accA[k] + accB[k]);
        *(bf16x8*)(smb + v * 72 + oct * 8) = sb8;
    }
    __syncthreads();
    // ---- phase 4: out projection (16x64)@(64x64); wave wv: col tiles wv, wv+2 ----
    // Store directly to global from MFMA regs (no obuf, no extra barrier).
    {
        bf16x8 oa0 = *(const bf16x8*)(smb + col * 72 + quad * 8);
        bf16x8 oa1 = *(const bf16x8*)(smb + col * 72 + 32 + quad * 8);
#pragma unroll
        for (int t = 0; t < 2; ++t) {
            int n0 = (wv + t * 2) * 16;
            bf16x8 b0 = *(const bf16x8*)(outB + (n0 + col) * 64 + quad * 8);
            bf16x8 b1 = *(const bf16x8*)(outB + (n0 + col) * 64 + 32 + quad * 8);
            f32x4 c = {0.f, 0.f, 0.f, 0.f};
            c = __builtin_amdgcn_mfma_f32_16x16x32_bf16(oa0, b0, c, 0, 0, 0);
            c = __builtin_amdgcn_mfma_f32_16x16x32_bf16(oa1, b1, c, 0, 0, 0);
            float bb = out_b[n0 + col];
#pragma unroll
            for (int r = 0; r < 4; ++r)
                out[(size_t)(s0 + quad * 4 + r) * 64 + n0 + col] = c[r] + bb;
        }
    }
}

extern "C" void kernel_launch(void* const* d_in, const int* in_sizes, int n_in,
                              void* d_out, int out_size, void* d_ws, size_t ws_size,
                              hipStream_t stream) {
    const float* x      = (const float*)d_in[0];
    const float* dw_w   = (const float*)d_in[1];
    const float* gn_w   = (const float*)d_in[2];
    const float* gn_b   = (const float*)d_in[3];
    const float* inp_w  = (const float*)d_in[4];
    const float* inp_b  = (const float*)d_in[5];
    const float* off_w  = (const float*)d_in[6];
    const float* off_b  = (const float*)d_in[7];
    const float* mask_w = (const float*)d_in[8];
    const float* mask_b = (const float*)d_in[9];
    const float* out_w  = (const float*)d_in[10];
    const float* out_b  = (const float*)d_in[11];

    char* B = (char*)d_ws;
    float*          partials = (float*)(B + 256);                // 64 KB
    unsigned short* xcb      = (unsigned short*)(B + 65792);     // 4 MB (bf16)
    unsigned short* x1b      = (unsigned short*)(B + 8454400);   // 4 MB
    unsigned short* x_tb     = (unsigned short*)(B + 12648704);  // 4 MB
    unsigned short* xpad     = (unsigned short*)(B + 16843008);  // 7.02 MB (fp16)
    unsigned short* WcatB    = (unsigned short*)(B + 30890240);  // 28 KB
    float*          bcat     = (float*)(B + 30918912);           // 1 KB
    unsigned short* inpB     = (unsigned short*)(B + 30919936);  // 8 KB
    unsigned short* outB     = (unsigned short*)(B + 30928128);  // 8 KB
    float* out = (float*)d_out;

    k_front<<<8792, 256, 0, stream>>>(x, dw_w, off_w, mask_w, off_b, mask_b,
                                      inp_w, out_w, WcatB, bcat, inpB, outB,
                                      x_tb, xcb, partials);
    k_mid<<<512 + 512 + 858, 256, 0, stream>>>(xcb, partials, gn_w, gn_b, x1b,
                                               x_tb, inpB, inp_b, xpad);
    k_main<<<2048, 128, 0, stream>>>(x1b, xpad, WcatB, bcat, outB, out_b, out);
}

// Round 4
// 153.532 us; speedup vs baseline: 1.3773x; 1.1568x over previous
//
#include <hip/hip_runtime.h>
#include <hip/hip_fp16.h>
#include <math.h>

#define SP 32768            // 32*32*32 voxels
#define PW 38               // padded volume width (zero ring around 34^3 logical)
#define PW2 (PW*PW)         // 1444
#define PVOX (PW*PW*PW)     // 54872
#define OMS 228             // om_s row stride (floats): 28-pt padded offs(2*84) + masks(2*28)

typedef short bf16x8 __attribute__((ext_vector_type(8)));
typedef unsigned short u16x4 __attribute__((ext_vector_type(4)));
typedef float f32x4 __attribute__((ext_vector_type(4)));

__device__ __forceinline__ unsigned short f2b(float f) {
    unsigned u = __float_as_uint(f);
    u = (u + 0x7FFFu + ((u >> 16) & 1u)) >> 16;   // RNE
    return (unsigned short)u;
}
__device__ __forceinline__ float b2f1(unsigned short s) {
    return __uint_as_float(((unsigned)s) << 16);
}
__device__ __forceinline__ __half2 h2(unsigned u) {
    return *reinterpret_cast<__half2*>(&u);
}
// block voxel tile = 2(d) x 2(h) x 4(w); tile grid = 16(d) x 16(h) x 8(w)
__device__ __forceinline__ int vox_of(int sb, int v) {
    int tw = sb & 7, th = (sb >> 3) & 15, td = sb >> 7;
    int vw = v & 3, vh = (v >> 2) & 1, vd = v >> 3;
    return (((td << 1) + vd) << 10) + (((th << 1) + vh) << 5) + (tw << 2) + vw;
}

// ====== K1: prep (bf16 B^T weights) + x transpose + dwconv(x4) + ring zero ======
__global__ void k_front(const float* __restrict__ x, const float* __restrict__ dw,
                        const float* __restrict__ off_w, const float* __restrict__ mask_w,
                        const float* __restrict__ off_b, const float* __restrict__ mask_b,
                        const float* __restrict__ inp_w, const float* __restrict__ out_w,
                        unsigned short* __restrict__ WcatB, float* __restrict__ bcat,
                        unsigned short* __restrict__ inpB, unsigned short* __restrict__ outB,
                        unsigned short* __restrict__ x_tb,
                        unsigned short* __restrict__ xcb, float* __restrict__ partials,
                        unsigned short* __restrict__ xpad) {
    int bb = blockIdx.x, tid = threadIdx.x;
    if (bb < 88) {                               // ---- weight prep ----
        int idx = bb * 256 + tid;
        int j = idx >> 6, k = idx & 63;
        if (j < 224) {
            float v = 0.f;
            if (j < 162) v = off_w[k * 162 + j];
            else if (j < 216) v = mask_w[k * 54 + (j - 162)];
            WcatB[j * 64 + k] = f2b(v);
            if (k == 0) bcat[j] = (j < 162) ? off_b[j] : (j < 216 ? mask_b[j - 162] : 0.f);
        } else if (j < 288) {
            outB[(j - 224) * 64 + k] = f2b(out_w[k * 64 + (j - 224)]);
        } else {
            inpB[(j - 288) * 64 + k] = f2b(inp_w[k * 64 + (j - 288)]);
        }
        return;
    }
    if (bb < 600) {                              // ---- x: NCDHW -> [s][c] bf16 ----
        __shared__ unsigned short tile[64][66];
        int s0 = (bb - 88) * 64;
        int row = tid >> 6, lane = tid & 63;
        for (int c = row; c < 64; c += 4)
            tile[c][lane] = f2b(x[(size_t)c * SP + s0 + lane]);
        __syncthreads();
        for (int r = row; r < 64; r += 4)
            x_tb[(size_t)(s0 + r) * 64 + lane] = tile[lane][r];
        return;
    }
    if (bb < 2648) {                             // ---- dwconv 3x3x3, 4 outputs/thread ----
        int b4 = bb - 600;
        int e4 = b4 * 256 + tid;                 // group of 4 voxels along w
        int c = e4 >> 13, s4 = (e4 & 8191) << 2;
        int d = s4 >> 10, h = (s4 >> 5) & 31, w0 = s4 & 31;   // w0 in {0,4,...,28}
        const float* xs = x + (size_t)c * SP;
        const float* wt = dw + c * 27;
        float a0 = 0.f, a1 = 0.f, a2 = 0.f, a3 = 0.f;
#pragma unroll
        for (int kd = 0; kd < 3; ++kd) {
            int zz = d + kd - 1; if ((unsigned)zz >= 32u) continue;
#pragma unroll
            for (int kh = 0; kh < 3; ++kh) {
                int yy = h + kh - 1; if ((unsigned)yy >= 32u) continue;
                const float* row = xs + (zz << 10) + (yy << 5) + w0;
                float4 L = *(const float4*)row;
                float xl = (w0 > 0) ? row[-1] : 0.f;
                float xr = (w0 < 28) ? row[4] : 0.f;
                const float* wr = wt + kd * 9 + kh * 3;
                float wm = wr[0], wc = wr[1], wp = wr[2];
                a0 = __builtin_fmaf(wm, xl,  __builtin_fmaf(wc, L.x, __builtin_fmaf(wp, L.y, a0)));
                a1 = __builtin_fmaf(wm, L.x, __builtin_fmaf(wc, L.y, __builtin_fmaf(wp, L.z, a1)));
                a2 = __builtin_fmaf(wm, L.y, __builtin_fmaf(wc, L.z, __builtin_fmaf(wp, L.w, a2)));
                a3 = __builtin_fmaf(wm, L.z, __builtin_fmaf(wc, L.w, __builtin_fmaf(wp, xr,  a3)));
            }
        }
        u16x4 o4; o4[0] = f2b(a0); o4[1] = f2b(a1); o4[2] = f2b(a2); o4[3] = f2b(a3);
        *(u16x4*)(xcb + (size_t)e4 * 4) = o4;
        __shared__ float rs[256], rq[256];
        rs[tid] = a0 + a1 + a2 + a3;
        rq[tid] = a0 * a0 + a1 * a1 + a2 * a2 + a3 * a3;
        __syncthreads();
        for (int off = 128; off > 0; off >>= 1) {
            if (tid < off) { rs[tid] += rs[tid + off]; rq[tid] += rq[tid + off]; }
            __syncthreads();
        }
        if (tid == 0) {
            partials[b4 * 2 + 0] = rs[0];
            partials[b4 * 2 + 1] = rq[0];
        }
        return;
    }
    // ---- ring zero (fp16): independent of everything else ----
    int cblk = bb - 2648;
    int j = tid >> 4, c4 = tid & 15;
    u16x4 z = {0, 0, 0, 0};
#pragma unroll
    for (int k = 0; k < 4; ++k) {
        int v = cblk * 64 + k * 16 + j;
        if (v >= PVOX) break;
        int zz = v / PW2, r = v - zz * PW2, yy = r / PW, xx = r - yy * PW;
        if (zz < 2 || zz > 33 || yy < 2 || yy > 33 || xx < 2 || xx > 33)
            *(u16x4*)(xpad + (size_t)v * 64 + c4 * 4) = z;
    }
}

// ========= K2: GN+GELU -> x1b  |  MFMA inproj -> xpad (fp16) =========
__global__ void k_mid(const unsigned short* __restrict__ xcb, const float* __restrict__ partials,
                      const float* __restrict__ gn_w, const float* __restrict__ gn_b,
                      unsigned short* __restrict__ x1b,
                      const unsigned short* __restrict__ x_tb,
                      const unsigned short* __restrict__ inpB,
                      const float* __restrict__ inp_b,
                      unsigned short* __restrict__ xpad) {
    int bb = blockIdx.x, tid = threadIdx.x;
    if (bb < 512) {                              // ---- GroupNorm(1,C)+GELU, transposed ----
        __shared__ float rs[256], rq[256];
        __shared__ unsigned short tile[64][66];
        float a = 0.f, b = 0.f;
        for (int i = tid; i < 2048; i += 256) { a += partials[2 * i]; b += partials[2 * i + 1]; }
        rs[tid] = a; rq[tid] = b;
        __syncthreads();
        for (int off = 128; off > 0; off >>= 1) {
            if (tid < off) { rs[tid] += rs[tid + off]; rq[tid] += rq[tid + off]; }
            __syncthreads();
        }
        const float Minv = 1.f / 2097152.f;
        float mu = rs[0] * Minv;
        float var = rq[0] * Minv - mu * mu;
        float rsq = rsqrtf(var + 1e-5f);
        int s0 = bb * 64;
        int row = tid >> 6, lane = tid & 63;
        for (int c = row; c < 64; c += 4) {
            float v = (b2f1(xcb[(size_t)c * SP + s0 + lane]) - mu) * rsq * gn_w[c] + gn_b[c];
            // gelu(tanh) = v * sigmoid(2t), t = 0.79788456*(v+0.044715 v^3)
            float t2 = 1.5957691216057308f * (v + 0.044715f * v * v * v);
            tile[c][lane] = f2b(v / (1.f + __expf(-t2)));
        }
        __syncthreads();
        for (int r = row; r < 64; r += 4)
            x1b[(size_t)(s0 + r) * 64 + lane] = tile[lane][r];
        return;
    }
    // ---- inproj: 4 waves x 16 voxels ----
    {
        int wv = tid >> 6, lane = tid & 63;
        int quad = lane >> 4, col = lane & 15;
        int s0 = (bb - 512) * 64 + wv * 16;
        bf16x8 a0 = *(const bf16x8*)(x_tb + (size_t)(s0 + col) * 64 + quad * 8);
        bf16x8 a1 = *(const bf16x8*)(x_tb + (size_t)(s0 + col) * 64 + 32 + quad * 8);
        int vp[4];
#pragma unroll
        for (int r = 0; r < 4; ++r) {
            int s = s0 + (quad << 2) + r;        // orig voxel (d,h,w) at 38-coord +2
            vp[r] = (((s >> 10) + 2) * PW + ((s >> 5) & 31) + 2) * PW + (s & 31) + 2;
        }
#pragma unroll
        for (int nt = 0; nt < 4; ++nt) {
            int n0 = nt * 16;
            bf16x8 b0 = *(const bf16x8*)(inpB + (n0 + col) * 64 + quad * 8);
            bf16x8 b1 = *(const bf16x8*)(inpB + (n0 + col) * 64 + 32 + quad * 8);
            f32x4 c = {0.f, 0.f, 0.f, 0.f};
            c = __builtin_amdgcn_mfma_f32_16x16x32_bf16(a0, b0, c, 0, 0, 0);
            c = __builtin_amdgcn_mfma_f32_16x16x32_bf16(a1, b1, c, 0, 0, 0);
            float bq = inp_b[n0 + col];
#pragma unroll
            for (int r = 0; r < 4; ++r)
                xpad[(size_t)vp[r] * 64 + n0 + col] =
                    __half_as_ushort(__float2half(c[r] + bq));
        }
    }
}

// ---- unrolled sampler; compile-time px/py/pz ----
template<int P0, int NP>
__device__ __forceinline__ void sampleN(const float* __restrict__ orow,
                                        const float* __restrict__ mrow,
                                        const char* __restrict__ volc,
                                        float xb, float yb, float zb,
                                        float* __restrict__ acc) {
#pragma unroll
    for (int i = 0; i < NP; ++i) {
        const int p = P0 + i;
        const int px = p % 3, py = (p / 3) % 3, pz = p / 9;
        float ox = orow[p * 3 + 0], oy = orow[p * 3 + 1], oz = orow[p * 3 + 2];
        float mk = mrow[p];
        float ix = __builtin_fmaf(0.25f, ox, xb + (float)px);
        float iy = __builtin_fmaf(0.5f, oy, yb + (float)py);
        float iz = __builtin_fmaf(0.5f, oz, zb + (float)pz);
        // clamp to [0,36]: OOB samples land wholly in the zero ring
        ix = fminf(fmaxf(ix, 0.f), 36.f);
        iy = fminf(fmaxf(iy, 0.f), 36.f);
        iz = fminf(fmaxf(iz, 0.f), 36.f);
        float xf = floorf(ix), yf = floorf(iy), zf = floorf(iz);
        float fx = ix - xf, fy = iy - yf, fz = iz - zf;
        float fi = __builtin_fmaf(zf, (float)PW2, __builtin_fmaf(yf, (float)PW, xf));
        int ib = ((int)fi) << 7;                 // 128 B per voxel row (fp16)
        const char* base = volc + ib;
        uint4 r000 = *(const uint4*)(base);
        uint4 r001 = *(const uint4*)(base + 128);
        uint4 r010 = *(const uint4*)(base + PW * 128);
        uint4 r011 = *(const uint4*)(base + PW * 128 + 128);
        uint4 r100 = *(const uint4*)(base + PW2 * 128);
        uint4 r101 = *(const uint4*)(base + PW2 * 128 + 128);
        uint4 r110 = *(const uint4*)(base + (PW2 + PW) * 128);
        uint4 r111 = *(const uint4*)(base + (PW2 + PW) * 128 + 128);
        __half2 fx2 = __float2half2_rn(fx);
        __half2 fy2 = __float2half2_rn(fy);
        __half2 fz2 = __float2half2_rn(fz);
        #define TRI(comp, ci)                                                   \
        {                                                                       \
            __half2 t0 = __hfma2(fx2, __hsub2(h2(r001.comp), h2(r000.comp)), h2(r000.comp)); \
            __half2 t1 = __hfma2(fx2, __hsub2(h2(r011.comp), h2(r010.comp)), h2(r010.comp)); \
            __half2 t2 = __hfma2(fx2, __hsub2(h2(r101.comp), h2(r100.comp)), h2(r100.comp)); \
            __half2 t3 = __hfma2(fx2, __hsub2(h2(r111.comp), h2(r110.comp)), h2(r110.comp)); \
            __half2 u0 = __hfma2(fy2, __hsub2(t1, t0), t0);                     \
            __half2 u1 = __hfma2(fy2, __hsub2(t3, t2), t2);                     \
            __half2 rr = __hfma2(fz2, __hsub2(u1, u0), u0);                     \
            float2 ff = __half22float2(rr);                                     \
            acc[2 * ci + 0] = __builtin_fmaf(mk, ff.x, acc[2 * ci + 0]);        \
            acc[2 * ci + 1] = __builtin_fmaf(mk, ff.y, acc[2 * ci + 1]);        \
        }
        TRI(x, 0) TRI(y, 1) TRI(z, 2) TRI(w, 3)
        #undef TRI
    }
}

// ========= K3: main — 2x2x4 voxel tile/block (L1-resident gathers), 2 waves =========
// 2 barriers; in-wave softmax; direct global store from MFMA regs.
__global__ void __launch_bounds__(128, 4) k_main(const unsigned short* __restrict__ x1b,
                                                 const unsigned short* __restrict__ xpad,
                                                 const unsigned short* __restrict__ WcatB,
                                                 const float* __restrict__ bcat,
                                                 const unsigned short* __restrict__ outB,
                                                 const float* __restrict__ out_b,
                                                 float* __restrict__ out) {
    __shared__ float om_s[16 * OMS];             // 14592 B: 28-pt padded offs+masks
    __shared__ unsigned short smb[16 * 72];      // 2304 B: sampled accum, bf16 (stride 72)
    int tid = threadIdx.x, wv = tid >> 6, lane = tid & 63;
    int quad = lane >> 4, col = lane & 15;
    // XCD swizzle over tiles: blocks sharing (blk&7) land on one XCD
    int sb = ((blockIdx.x & 7) << 8) | (blockIdx.x >> 3);
    // ---- phase 1: offset+mask GEMM (16x64)@(64x224); 7 jt tiles per wave ----
    {
        int sv = vox_of(sb, col);                // lane's A-row voxel
        bf16x8 a0 = *(const bf16x8*)(x1b + (size_t)sv * 64 + quad * 8);
        bf16x8 a1 = *(const bf16x8*)(x1b + (size_t)sv * 64 + 32 + quad * 8);
        for (int jt = wv; jt < 14; jt += 2) {
            int n0 = jt * 16;
            bf16x8 b0 = *(const bf16x8*)(WcatB + (n0 + col) * 64 + quad * 8);
            bf16x8 b1 = *(const bf16x8*)(WcatB + (n0 + col) * 64 + 32 + quad * 8);
            f32x4 c = {0.f, 0.f, 0.f, 0.f};
            c = __builtin_amdgcn_mfma_f32_16x16x32_bf16(a0, b0, c, 0, 0, 0);
            c = __builtin_amdgcn_mfma_f32_16x16x32_bf16(a1, b1, c, 0, 0, 0);
            float bb = bcat[n0 + col];
            // remap feature n -> padded 28-pt slot
            int n = n0 + col, slot;
            if (n < 162) slot = n + ((n >= 81) ? 3 : 0);
            else { int n2 = n - 162; slot = 168 + n2 + ((n2 >= 27) ? 1 : 0); }
            if (n < 216) {
#pragma unroll
                for (int r = 0; r < 4; ++r)
                    om_s[(quad * 4 + r) * OMS + slot] = c[r] + bb;
            }
        }
    }
    __syncthreads();
    // ---- phase 2: wave-parallel softmax; 16 rows/wave (8 vox x 2 grp), 4 lanes/row ----
    // Same wave consumes its own rows in phase 3 -> no barrier needed after this.
    {
        int row = lane >> 2, sub = lane & 3;     // 4 lanes per row, 7 pts per lane
        int vloc = wv * 8 + (row >> 1), g = row & 1;
        float* m = &om_s[vloc * OMS + 168 + g * 28];
        float mv[7];
        float mx = -1e30f;
#pragma unroll
        for (int i = 0; i < 7; ++i) {
            int p = sub * 7 + i;
            mv[i] = (p < 27) ? m[p] : -1e30f;
            mx = fmaxf(mx, mv[i]);
        }
        mx = fmaxf(mx, __shfl_xor(mx, 1));
        mx = fmaxf(mx, __shfl_xor(mx, 2));
        float e[7], sm = 0.f;
#pragma unroll
        for (int i = 0; i < 7; ++i) { e[i] = __expf(mv[i] - mx); sm += e[i]; }
        sm += __shfl_xor(sm, 1);
        sm += __shfl_xor(sm, 2);
        float inv = 1.f / sm;
#pragma unroll
        for (int i = 0; i < 7; ++i) {
            int p = sub * 7 + i;
            if (p < 27) m[p] = e[i] * inv;
        }
    }
    // ---- phase 3: sampling; wave wv owns voxels wv*8..wv*8+7; 27 points/lane ----
    {
        int v = wv * 8 + (lane >> 3);            // local voxel 0..15
        int oct = lane & 7, gg = oct >> 2;       // channels oct*8..oct*8+7
        int sv = vox_of(sb, v);
        float zb = (float)((sv >> 10) + 1);
        float yb = (float)(((sv >> 5) & 31) + 1);
        float xb = (float)((sv & 31) + 1);
        const float* orow = &om_s[v * OMS + gg * 84];
        const float* mrow = &om_s[v * OMS + 168 + gg * 28];
        const char* volc = (const char*)xpad + oct * 16;    // 8 fp16 channels
        float acc[8] = {0.f, 0.f, 0.f, 0.f, 0.f, 0.f, 0.f, 0.f};
        sampleN<0, 27>(orow, mrow, volc, xb, yb, zb, acc);
        bf16x8 sb8;
#pragma unroll
        for (int k = 0; k < 8; ++k) sb8[k] = (short)f2b(acc[k]);
        *(bf16x8*)(smb + v * 72 + oct * 8) = sb8;
    }
    __syncthreads();
    // ---- phase 4: out projection (16x64)@(64x64); wave wv: col tiles wv, wv+2 ----
    // Store directly to global from MFMA regs (no obuf, no extra barrier).
    {
        bf16x8 oa0 = *(const bf16x8*)(smb + col * 72 + quad * 8);
        bf16x8 oa1 = *(const bf16x8*)(smb + col * 72 + 32 + quad * 8);
        int vr[4];
#pragma unroll
        for (int r = 0; r < 4; ++r) vr[r] = vox_of(sb, quad * 4 + r);
#pragma unroll
        for (int t = 0; t < 2; ++t) {
            int n0 = (wv + t * 2) * 16;
            bf16x8 b0 = *(const bf16x8*)(outB + (n0 + col) * 64 + quad * 8);
            bf16x8 b1 = *(const bf16x8*)(outB + (n0 + col) * 64 + 32 + quad * 8);
            f32x4 c = {0.f, 0.f, 0.f, 0.f};
            c = __builtin_amdgcn_mfma_f32_16x16x32_bf16(oa0, b0, c, 0, 0, 0);
            c = __builtin_amdgcn_mfma_f32_16x16x32_bf16(oa1, b1, c, 0, 0, 0);
            float bb = out_b[n0 + col];
#pragma unroll
            for (int r = 0; r < 4; ++r)
                out[(size_t)vr[r] * 64 + n0 + col] = c[r] + bb;
        }
    }
}

extern "C" void kernel_launch(void* const* d_in, const int* in_sizes, int n_in,
                              void* d_out, int out_size, void* d_ws, size_t ws_size,
                              hipStream_t stream) {
    const float* x      = (const float*)d_in[0];
    const float* dw_w   = (const float*)d_in[1];
    const float* gn_w   = (const float*)d_in[2];
    const float* gn_b   = (const float*)d_in[3];
    const float* inp_w  = (const float*)d_in[4];
    const float* inp_b  = (const float*)d_in[5];
    const float* off_w  = (const float*)d_in[6];
    const float* off_b  = (const float*)d_in[7];
    const float* mask_w = (const float*)d_in[8];
    const float* mask_b = (const float*)d_in[9];
    const float* out_w  = (const float*)d_in[10];
    const float* out_b  = (const float*)d_in[11];

    char* B = (char*)d_ws;
    float*          partials = (float*)(B + 256);                // 64 KB region (uses 16 KB)
    unsigned short* xcb      = (unsigned short*)(B + 65792);     // 4 MB (bf16)
    unsigned short* x1b      = (unsigned short*)(B + 8454400);   // 4 MB
    unsigned short* x_tb     = (unsigned short*)(B + 12648704);  // 4 MB
    unsigned short* xpad     = (unsigned short*)(B + 16843008);  // 7.02 MB (fp16)
    unsigned short* WcatB    = (unsigned short*)(B + 30890240);  // 28 KB
    float*          bcat     = (float*)(B + 30918912);           // 1 KB
    unsigned short* inpB     = (unsigned short*)(B + 30919936);  // 8 KB
    unsigned short* outB     = (unsigned short*)(B + 30928128);  // 8 KB
    float* out = (float*)d_out;

    k_front<<<88 + 512 + 2048 + 858, 256, 0, stream>>>(x, dw_w, off_w, mask_w, off_b, mask_b,
                                                       inp_w, out_w, WcatB, bcat, inpB, outB,
                                                       x_tb, xcb, partials, xpad);
    k_mid<<<512 + 512, 256, 0, stream>>>(xcb, partials, gn_w, gn_b, x1b,
                                         x_tb, inpB, inp_b, xpad);
    k_main<<<2048, 128, 0, stream>>>(x1b, xpad, WcatB, bcat, outB, out_b, out);
}